// Round 10
// baseline (917.123 us; speedup 1.0000x reference)
//
#include <hip/hip_runtime.h>
#include <hip/hip_bf16.h>

#define NN 50000
#define NE 1600000
#define FIN 64
#define H 128
#define NL 5
#define NG 512
#define NC 10
#define NCH 6          // src chunks (8192 rows = 2 MB bf16 each)
#define NSEG (NN*NCH)  // 300000 CSR segments
#define SCANB 294      // scan blocks (294*1024 >= 300001)
#define NPB 32         // nodes per k_layer block
#define NLBLK 1563     // ceil(NN/NPB)

typedef __attribute__((ext_vector_type(8))) short short8;
typedef __attribute__((ext_vector_type(4))) float f32x4;

// ws word offsets — total 9,113,344 words (36.45 MB)
// cur/blksum/pooled ALIAS h2b (disjoint lifetimes)
#define OFF_H2A   0            // bf16 h ping (3.2M words)
#define OFF_H2B   3200000      // bf16 h pong (3.2M words)
#define OFF_CUR   3200000      // 300001 ints, transient (CSR build only)
#define OFF_BLK   3600000      // 294 ints, transient (scan block sums)
#define OFF_POOL  3200000      // 65536 unsigned, transient (after layer3)
#define OFF_OFF   6400000      // 300064 ints (padded CSR starts, persistent)
#define OFF_CSR   6700064      // 2,265,824 packed words (ushort src | bf16 w << 16)
#define OFF_FWF   8965888      // 245760 shorts (5 x 128x384 bf16 frag)
#define OFF_FWHH  9088768      // 49152 shorts -> end 9113344

__device__ __forceinline__ short rne_bf16(float f){
    unsigned u = __float_as_uint(f);
    unsigned r = (u + 0x7FFFu + ((u >> 16) & 1u)) >> 16;
    return (short)r;
}
__device__ __forceinline__ float bf_lo(unsigned v){ return __uint_as_float(v << 16); }
__device__ __forceinline__ float bf_hi(unsigned v){ return __uint_as_float(v & 0xFFFF0000u); }
__device__ __forceinline__ int chk(int s){ int c = s >> 13; return c > (NCH-1) ? (NCH-1) : c; }

// ---------- CSR build (per-(dst,chunk) sublists, chunk-ordered per dst) ----------

__global__ void k_hist(const int* __restrict__ ei, int* __restrict__ cnt){
    int e0 = (blockIdx.x*256 + threadIdx.x)*4;
    if (e0 + 3 < NE){
        int4 s = *(const int4*)(ei + e0);
        int4 d = *(const int4*)(ei + NE + e0);
        atomicAdd(&cnt[d.x*NCH + chk(s.x)], 1);
        atomicAdd(&cnt[d.y*NCH + chk(s.y)], 1);
        atomicAdd(&cnt[d.z*NCH + chk(s.z)], 1);
        atomicAdd(&cnt[d.w*NCH + chk(s.w)], 1);
    } else {
        for (int e = e0; e < NE; ++e)
            atomicAdd(&cnt[ei[NE + e]*NCH + chk(ei[e])], 1);
    }
}

// hierarchical exclusive scan of 300001 counts padded to multiples of 4
__global__ void k_scan1(const int* __restrict__ cnt, int* __restrict__ blksum){
    __shared__ int s[1024];
    int t = threadIdx.x, i = blockIdx.x*1024 + t;
    int v = (i <= NSEG) ? ((cnt[i] + 3) & ~3) : 0;
    s[t] = v; __syncthreads();
    for (int o = 512; o > 0; o >>= 1){ if (t < o) s[t] += s[t + o]; __syncthreads(); }
    if (t == 0) blksum[blockIdx.x] = s[0];
}
__global__ void k_scan2(int* __restrict__ blksum){
    __shared__ int s[512];
    int t = threadIdx.x;
    int v = (t < SCANB) ? blksum[t] : 0;
    s[t] = v; __syncthreads();
    for (int o = 1; o < 512; o <<= 1){
        int u = (t >= o) ? s[t - o] : 0; __syncthreads();
        s[t] += u; __syncthreads();
    }
    if (t < SCANB) blksum[t] = s[t] - v;     // exclusive
}
__global__ void k_scan3(const int* __restrict__ cnt, const int* __restrict__ blksum,
                        int* __restrict__ off, int* __restrict__ cur){
    __shared__ int s[1024];
    int t = threadIdx.x, i = blockIdx.x*1024 + t;
    int v = (i <= NSEG) ? ((cnt[i] + 3) & ~3) : 0;
    s[t] = v; __syncthreads();
    for (int o = 1; o < 1024; o <<= 1){
        int u = (t >= o) ? s[t - o] : 0; __syncthreads();
        s[t] += u; __syncthreads();
    }
    int e = s[t] - v + blksum[blockIdx.x];   // exclusive
    if (i <= NSEG){ off[i] = e; cur[i] = e; }
}

// packed fill: ONE 4-byte store per edge; csr pre-zeroed so pad slots are
// (src=0, w=+0.0) dummy edges. 4 independent edges per thread.
__global__ void k_fill(const int* __restrict__ ei, const float* __restrict__ ew,
                       int* __restrict__ cur, unsigned* __restrict__ csr){
    int e0 = (blockIdx.x*256 + threadIdx.x)*4;
    if (e0 + 3 < NE){
        int4   s = *(const int4*)(ei + e0);
        int4   d = *(const int4*)(ei + NE + e0);
        float4 w = *(const float4*)(ew + e0);
        int p0 = atomicAdd(&cur[d.x*NCH + chk(s.x)], 1);
        int p1 = atomicAdd(&cur[d.y*NCH + chk(s.y)], 1);
        int p2 = atomicAdd(&cur[d.z*NCH + chk(s.z)], 1);
        int p3 = atomicAdd(&cur[d.w*NCH + chk(s.w)], 1);
        csr[p0] = (unsigned)s.x | (((unsigned)(ushort)rne_bf16(w.x)) << 16);
        csr[p1] = (unsigned)s.y | (((unsigned)(ushort)rne_bf16(w.y)) << 16);
        csr[p2] = (unsigned)s.z | (((unsigned)(ushort)rne_bf16(w.z)) << 16);
        csr[p3] = (unsigned)s.w | (((unsigned)(ushort)rne_bf16(w.w)) << 16);
    } else {
        for (int e = e0; e < NE; ++e){
            int src = ei[e], dst = ei[NE + e];
            int pos = atomicAdd(&cur[dst*NCH + chk(src)], 1);
            csr[pos] = (unsigned)src | (((unsigned)(ushort)rne_bf16(ew[e])) << 16);
        }
    }
}

// ---------- one-time prep ----------

__global__ void k_pad(const float* __restrict__ x, ushort* __restrict__ h2a){
    int idx = blockIdx.x*256 + threadIdx.x;   // 0..799999
    int n = idx >> 4, f8 = idx & 15;
    short8 v;
    if (f8 < 8){
        float4 a = *(const float4*)(x + n*FIN + f8*8);
        float4 b = *(const float4*)(x + n*FIN + f8*8 + 4);
        v[0]=rne_bf16(a.x); v[1]=rne_bf16(a.y); v[2]=rne_bf16(a.z); v[3]=rne_bf16(a.w);
        v[4]=rne_bf16(b.x); v[5]=rne_bf16(b.y); v[6]=rne_bf16(b.z); v[7]=rne_bf16(b.w);
    } else {
        v[0]=0; v[1]=0; v[2]=0; v[3]=0; v[4]=0; v[5]=0; v[6]=0; v[7]=0;
    }
    *(short8*)(h2a + idx*8) = v;
}

// fragWf[l] = bf16-frag( W_l @ w_ih^T )   [K=128][N=384]
__global__ void k_fuse(const float* __restrict__ W, const float* __restrict__ wih,
                       short* __restrict__ fwf){
    int idx = blockIdx.x*256 + threadIdx.x;   // 0..245759
    int l = idx / 49152;
    int r = idx % 49152;
    int k = r / 384, n = r % 384;
    const float4* wl = (const float4*)(W + l*16384 + k*128);
    const float4* wi = (const float4*)(wih + n*128);
    float acc = 0.f;
    #pragma unroll 8
    for (int c = 0; c < 32; ++c){
        float4 a = wl[c], b = wi[c];
        acc += a.x*b.x + a.y*b.y + a.z*b.z + a.w*b.w;
    }
    int lane = ((k>>3)&3)*16 + (n&15);
    fwf[l*49152 + (((n>>4)*4 + (k>>5))*64 + lane)*8 + (k&7)] = rne_bf16(acc);
}

__global__ void k_cvt_whh(const float* __restrict__ whh, short* __restrict__ fwhh){
    int idx = blockIdx.x*256 + threadIdx.x;   // 0..49151
    int k = idx / 384, n = idx % 384;
    float v = whh[n*128 + k];
    int lane = ((k>>3)&3)*16 + (n&15);
    fwhh[(((n>>4)*4 + (k>>5))*64 + lane)*8 + (k&7)] = rne_bf16(v);
}

__global__ void k_init_pool(unsigned* __restrict__ p){
    p[blockIdx.x*256 + threadIdx.x] = 0x007FFFFFu;   // enc(-inf)
}

// ---------- fused layer: aggregate -> dual MFMA GEMM -> register GRU ----------
// 1024 threads = 16 waves, 32 nodes per block.
// Phase 1: per-wave shape identical to proven R2 (2 nodes/wave, chunk-ordered
//          single-span walk, pad-4 guard).
// Phase 2: wave w owns row-tile rt=w>>3 and cols (w&7)*16..+15 of each of the
//          3 sections. Blocks halved -> B-fragment traffic halved (600->300MB),
//          16 waves x 2 blocks = 32 waves/CU.
__global__ __launch_bounds__(1024)
void k_layer(const ushort* __restrict__ h2r, ushort* __restrict__ h2w,
             const int* __restrict__ off, const unsigned* __restrict__ csr,
             const short* __restrict__ fwf, const short* __restrict__ fwhh,
             const float* __restrict__ b_ih, const float* __restrict__ b_hh,
             const int* __restrict__ batch, unsigned* __restrict__ pooled,
             int last){
    __shared__ ushort tl[32*136];             // row stride 136 ushorts (16B-aligned)
    int tid = threadIdx.x;
    int n0 = blockIdx.x * NPB;
    int wave = tid >> 6, lane = tid & 63;
    int lane_lo = lane & 15, quad = lane >> 4;
    int grp = lane >> 4, fl = lane & 15;

    // ---- phase 1: pull-aggregate 2 nodes per wave into LDS (bf16) ----
    for (int sub = 0; sub < 2; ++sub){
        int node = n0 + wave*2 + sub;
        int start = 0, end = 0;
        if (node < NN){
            start = __builtin_amdgcn_readfirstlane(off[node*NCH]);
            end   = __builtin_amdgcn_readfirstlane(off[node*NCH + NCH]);
        }
        float a0=0.f,a1=0.f,a2=0.f,a3=0.f,a4=0.f,a5=0.f,a6=0.f,a7=0.f;
        const ushort* hb = h2r + fl*8;
        for (int i = start; i < end; i += 16){
            int ii = i + grp*4;
            if (ii < end){                    // pad-4 guard (end is 4-aligned)
                uint4 c = *(const uint4*)(csr + ii);
                uint4 v0 = *(const uint4*)(hb + (c.x & 0xFFFFu)*H);
                uint4 v1 = *(const uint4*)(hb + (c.y & 0xFFFFu)*H);
                uint4 v2 = *(const uint4*)(hb + (c.z & 0xFFFFu)*H);
                uint4 v3 = *(const uint4*)(hb + (c.w & 0xFFFFu)*H);
                float w0 = bf_hi(c.x), w1 = bf_hi(c.y), w2 = bf_hi(c.z), w3 = bf_hi(c.w);
                a0 += w0*bf_lo(v0.x); a1 += w0*bf_hi(v0.x); a2 += w0*bf_lo(v0.y); a3 += w0*bf_hi(v0.y);
                a4 += w0*bf_lo(v0.z); a5 += w0*bf_hi(v0.z); a6 += w0*bf_lo(v0.w); a7 += w0*bf_hi(v0.w);
                a0 += w1*bf_lo(v1.x); a1 += w1*bf_hi(v1.x); a2 += w1*bf_lo(v1.y); a3 += w1*bf_hi(v1.y);
                a4 += w1*bf_lo(v1.z); a5 += w1*bf_hi(v1.z); a6 += w1*bf_lo(v1.w); a7 += w1*bf_hi(v1.w);
                a0 += w2*bf_lo(v2.x); a1 += w2*bf_hi(v2.x); a2 += w2*bf_lo(v2.y); a3 += w2*bf_hi(v2.y);
                a4 += w2*bf_lo(v2.z); a5 += w2*bf_hi(v2.z); a6 += w2*bf_lo(v2.w); a7 += w2*bf_hi(v2.w);
                a0 += w3*bf_lo(v3.x); a1 += w3*bf_hi(v3.x); a2 += w3*bf_lo(v3.y); a3 += w3*bf_hi(v3.y);
                a4 += w3*bf_lo(v3.z); a5 += w3*bf_hi(v3.z); a6 += w3*bf_lo(v3.w); a7 += w3*bf_hi(v3.w);
            }
        }
        // reduce across the 4 groups (each held a disjoint edge subset)
        a0 += __shfl_xor(a0,16); a1 += __shfl_xor(a1,16); a2 += __shfl_xor(a2,16); a3 += __shfl_xor(a3,16);
        a4 += __shfl_xor(a4,16); a5 += __shfl_xor(a5,16); a6 += __shfl_xor(a6,16); a7 += __shfl_xor(a7,16);
        a0 += __shfl_xor(a0,32); a1 += __shfl_xor(a1,32); a2 += __shfl_xor(a2,32); a3 += __shfl_xor(a3,32);
        a4 += __shfl_xor(a4,32); a5 += __shfl_xor(a5,32); a6 += __shfl_xor(a6,32); a7 += __shfl_xor(a7,32);
        if (lane < 16){
            short8 hbv;
            hbv[0]=rne_bf16(a0); hbv[1]=rne_bf16(a1); hbv[2]=rne_bf16(a2); hbv[3]=rne_bf16(a3);
            hbv[4]=rne_bf16(a4); hbv[5]=rne_bf16(a5); hbv[6]=rne_bf16(a6); hbv[7]=rne_bf16(a7);
            *(short8*)(tl + (wave*2 + sub)*136 + fl*8) = hbv;
        }
    }
    __syncthreads();

    // ---- phase 2: dual GEMM; wave w: row-tile rt=w>>3, col slice (w&7) ----
    int rt = wave >> 3, wc = wave & 7;
    f32x4 ai[3], ah[3];                       // [section]
    #pragma unroll
    for (int i = 0; i < 3; ++i){ ai[i] = (f32x4){0.f,0.f,0.f,0.f}; ah[i] = (f32x4){0.f,0.f,0.f,0.f}; }

    const ushort* arow_t = tl + (rt*16 + lane_lo)*136;
    const ushort* arow_h = h2r + (size_t)(n0 + rt*16 + lane_lo)*H;
    #pragma unroll
    for (int kt = 0; kt < 4; ++kt){
        short8 at  = *(const short8*)(arow_t + kt*32 + quad*8);
        short8 ahh = *(const short8*)(arow_h + kt*32 + quad*8);
        #pragma unroll
        for (int s = 0; s < 3; ++s){
            int tile = (s*8 + wc)*4 + kt;
            short8 bi = *(const short8*)(fwf  + tile*512 + lane*8);
            short8 bh = *(const short8*)(fwhh + tile*512 + lane*8);
            ai[s] = __builtin_amdgcn_mfma_f32_16x16x32_bf16(at,  bi, ai[s], 0, 0, 0);
            ah[s] = __builtin_amdgcn_mfma_f32_16x16x32_bf16(ahh, bh, ah[s], 0, 0, 0);
        }
    }

    // ---- phase 3: register-resident GRU update (+ fused pool on last) ----
    {
        int j = wc*16 + lane_lo;
        float bir = b_ih[j], biz = b_ih[128 + j], bin_ = b_ih[256 + j];
        float bhr = b_hh[j], bhz = b_hh[128 + j], bhn  = b_hh[256 + j];
        #pragma unroll
        for (int r = 0; r < 4; ++r){
            int row = n0 + rt*16 + quad*4 + r;
            float gir = ai[0][r] + bir, ghr = ah[0][r] + bhr;
            float giz = ai[1][r] + biz, ghz = ah[1][r] + bhz;
            float gin = ai[2][r] + bin_, ghn = ah[2][r] + bhn;
            float rr = 1.f/(1.f + __expf(-(gir + ghr)));
            float zz = 1.f/(1.f + __expf(-(giz + ghz)));
            float nn = tanhf(gin + rr*ghn);
            float ho = __uint_as_float(((unsigned)h2r[(size_t)row*H + j]) << 16);
            float hv = (1.f - zz)*nn + zz*ho;
            if (row < NN){
                if (!last){
                    h2w[(size_t)row*H + j] = (ushort)rne_bf16(hv);
                } else {
                    int g = batch[row];
                    unsigned u = __float_as_uint(hv);
                    u = (u & 0x80000000u) ? ~u : (u | 0x80000000u);
                    atomicMax(pooled + g*H + j, u);
                }
            }
        }
    }
}

// ---------- tail ----------

__global__ void k_head(const unsigned* __restrict__ pooled,
                       const float* __restrict__ d1w, const float* __restrict__ d1b,
                       const float* __restrict__ d2w, const float* __restrict__ d2b,
                       float* __restrict__ out){
    __shared__ float sp[128];
    __shared__ float shid[512];
    int g = blockIdx.x, tid = threadIdx.x;
    if (tid < 128){
        unsigned u = pooled[g*H + tid];
        sp[tid] = __uint_as_float((u & 0x80000000u) ? (u ^ 0x80000000u) : ~u);
    }
    __syncthreads();
    for (int o = tid; o < 512; o += 256){
        float acc = d1b[o];
        for (int k = 0; k < H; ++k) acc += sp[k] * d1w[o*H + k];
        shid[o] = fmaxf(acc, 0.f);
    }
    __syncthreads();
    if (tid < NC){
        float acc = d2b[tid];
        for (int o = 0; o < 512; ++o) acc += shid[o] * d2w[tid*512 + o];
        out[g*NC + tid] = acc;
    }
}

extern "C" void kernel_launch(void* const* d_in, const int* in_sizes, int n_in,
                              void* d_out, int out_size, void* d_ws, size_t ws_size,
                              hipStream_t stream){
    const float* x     = (const float*)d_in[0];
    const int*   ei    = (const int*)d_in[1];
    const int*   batch = (const int*)d_in[2];
    const float* ew    = (const float*)d_in[3];
    const float* W     = (const float*)d_in[4];
    const float* wih   = (const float*)d_in[5];
    const float* whh   = (const float*)d_in[6];
    const float* bih   = (const float*)d_in[7];
    const float* bhh   = (const float*)d_in[8];
    const float* d1w   = (const float*)d_in[9];
    const float* d1b   = (const float*)d_in[10];
    const float* d2w   = (const float*)d_in[11];
    const float* d2b   = (const float*)d_in[12];
    float* out = (float*)d_out;

    float*  ws  = (float*)d_ws;
    ushort* h2a = (ushort*)(ws + OFF_H2A);
    ushort* h2b = (ushort*)(ws + OFF_H2B);
    int*    cur = (int*)(ws + OFF_CUR);      // aliases h2b (dead before layer0)
    int*    blk = (int*)(ws + OFF_BLK);      // aliases h2b (scan only)
    unsigned* pooled = (unsigned*)(ws + OFF_POOL); // aliases h2b (init after layer3)
    int*    off = (int*)(ws + OFF_OFF);
    unsigned* csr = (unsigned*)(ws + OFF_CSR);
    short*  fwf  = (short*)(ws + OFF_FWF);
    short*  fwhh = (short*)(ws + OFF_FWHH);

    hipMemsetAsync(cur, 0, (NSEG + 1)*sizeof(int), stream);
    hipMemsetAsync(csr, 0, 2265824*sizeof(unsigned), stream);   // pad slots = dummy edges
    k_hist<<<1563, 256, 0, stream>>>(ei, cur);
    k_scan1<<<SCANB, 1024, 0, stream>>>(cur, blk);
    k_scan2<<<1, 512, 0, stream>>>(blk);
    k_scan3<<<SCANB, 1024, 0, stream>>>(cur, blk, off, cur);
    k_fill<<<1563, 256, 0, stream>>>(ei, ew, cur, csr);

    k_fuse<<<960, 256, 0, stream>>>(W, wih, fwf);
    k_cvt_whh<<<192, 256, 0, stream>>>(whh, fwhh);
    k_pad<<<3125, 256, 0, stream>>>(x, h2a);

    for (int l = 0; l < NL; ++l){
        ushort* h2r = (l & 1) ? h2b : h2a;
        ushort* h2w = (l & 1) ? h2a : h2b;
        if (l == NL-1) k_init_pool<<<256, 256, 0, stream>>>(pooled);  // after last h2b read
        k_layer<<<NLBLK, 1024, 0, stream>>>(h2r, h2w, off, csr,
                                            fwf + (size_t)l*49152, fwhh, bih, bhh,
                                            batch, pooled, (l == NL-1) ? 1 : 0);
    }

    k_head<<<NG, 256, 0, stream>>>(pooled, d1w, d1b, d2w, d2b, out);
}

// Round 11
// 825.382 us; speedup vs baseline: 1.1111x; 1.1111x over previous
//
#include <hip/hip_runtime.h>
#include <hip/hip_bf16.h>

#define NN 50000
#define NE 1600000
#define FIN 64
#define H 128
#define NL 5
#define NG 512
#define NC 10
#define NCH 6          // src chunks (8192 rows = 2 MB bf16 each)
#define NSEG (NN*NCH)  // 300000 CSR segments
#define SCANB 294      // scan blocks (294*1024 >= 300001)

typedef __attribute__((ext_vector_type(8))) short short8;
typedef __attribute__((ext_vector_type(4))) float f32x4;
typedef __attribute__((ext_vector_type(4))) unsigned uint4v;

// ws word offsets — total 9,113,344 words (36.45 MB)
// cur/blksum/pooled ALIAS h2b (disjoint lifetimes)
#define OFF_H2A   0            // bf16 h ping (3.2M words)
#define OFF_H2B   3200000      // bf16 h pong (3.2M words)
#define OFF_CUR   3200000      // 300001 ints, transient (CSR build only)
#define OFF_BLK   3600000      // 294 ints, transient (scan block sums)
#define OFF_POOL  3200000      // 65536 unsigned, transient (after layer3)
#define OFF_OFF   6400000      // 300064 ints (padded CSR starts, persistent)
#define OFF_CSR   6700064      // 2,265,824 packed words (ushort src | bf16 w << 16)
#define OFF_FWF   8965888      // 245760 shorts (5 x 128x384 bf16 frag)
#define OFF_FWHH  9088768      // 49152 shorts -> end 9113344

__device__ __forceinline__ short rne_bf16(float f){
    unsigned u = __float_as_uint(f);
    unsigned r = (u + 0x7FFFu + ((u >> 16) & 1u)) >> 16;
    return (short)r;
}
__device__ __forceinline__ float bf_lo(unsigned v){ return __uint_as_float(v << 16); }
__device__ __forceinline__ float bf_hi(unsigned v){ return __uint_as_float(v & 0xFFFF0000u); }
__device__ __forceinline__ int chk(int s){ int c = s >> 13; return c > (NCH-1) ? (NCH-1) : c; }

// ---------- CSR build (per-(dst,chunk) sublists, chunk-ordered per dst) ----------

__global__ void k_hist(const int* __restrict__ ei, int* __restrict__ cnt){
    int e0 = (blockIdx.x*256 + threadIdx.x)*4;
    if (e0 + 3 < NE){
        int4 s = *(const int4*)(ei + e0);
        int4 d = *(const int4*)(ei + NE + e0);
        atomicAdd(&cnt[d.x*NCH + chk(s.x)], 1);
        atomicAdd(&cnt[d.y*NCH + chk(s.y)], 1);
        atomicAdd(&cnt[d.z*NCH + chk(s.z)], 1);
        atomicAdd(&cnt[d.w*NCH + chk(s.w)], 1);
    } else {
        for (int e = e0; e < NE; ++e)
            atomicAdd(&cnt[ei[NE + e]*NCH + chk(ei[e])], 1);
    }
}

// hierarchical exclusive scan of 300001 counts padded to multiples of 4
__global__ void k_scan1(const int* __restrict__ cnt, int* __restrict__ blksum){
    __shared__ int s[1024];
    int t = threadIdx.x, i = blockIdx.x*1024 + t;
    int v = (i <= NSEG) ? ((cnt[i] + 3) & ~3) : 0;
    s[t] = v; __syncthreads();
    for (int o = 512; o > 0; o >>= 1){ if (t < o) s[t] += s[t + o]; __syncthreads(); }
    if (t == 0) blksum[blockIdx.x] = s[0];
}
__global__ void k_scan2(int* __restrict__ blksum){
    __shared__ int s[512];
    int t = threadIdx.x;
    int v = (t < SCANB) ? blksum[t] : 0;
    s[t] = v; __syncthreads();
    for (int o = 1; o < 512; o <<= 1){
        int u = (t >= o) ? s[t - o] : 0; __syncthreads();
        s[t] += u; __syncthreads();
    }
    if (t < SCANB) blksum[t] = s[t] - v;     // exclusive
}
__global__ void k_scan3(const int* __restrict__ cnt, const int* __restrict__ blksum,
                        int* __restrict__ off, int* __restrict__ cur){
    __shared__ int s[1024];
    int t = threadIdx.x, i = blockIdx.x*1024 + t;
    int v = (i <= NSEG) ? ((cnt[i] + 3) & ~3) : 0;
    s[t] = v; __syncthreads();
    for (int o = 1; o < 1024; o <<= 1){
        int u = (t >= o) ? s[t - o] : 0; __syncthreads();
        s[t] += u; __syncthreads();
    }
    int e = s[t] - v + blksum[blockIdx.x];   // exclusive
    if (i <= NSEG){ off[i] = e; cur[i] = e; }
}

// packed fill: ONE 4-byte store per edge; csr pre-zeroed so pad slots are
// (src=0, w=+0.0) dummy edges. 4 independent edges per thread.
__global__ void k_fill(const int* __restrict__ ei, const float* __restrict__ ew,
                       int* __restrict__ cur, unsigned* __restrict__ csr){
    int e0 = (blockIdx.x*256 + threadIdx.x)*4;
    if (e0 + 3 < NE){
        int4   s = *(const int4*)(ei + e0);
        int4   d = *(const int4*)(ei + NE + e0);
        float4 w = *(const float4*)(ew + e0);
        int p0 = atomicAdd(&cur[d.x*NCH + chk(s.x)], 1);
        int p1 = atomicAdd(&cur[d.y*NCH + chk(s.y)], 1);
        int p2 = atomicAdd(&cur[d.z*NCH + chk(s.z)], 1);
        int p3 = atomicAdd(&cur[d.w*NCH + chk(s.w)], 1);
        csr[p0] = (unsigned)s.x | (((unsigned)(ushort)rne_bf16(w.x)) << 16);
        csr[p1] = (unsigned)s.y | (((unsigned)(ushort)rne_bf16(w.y)) << 16);
        csr[p2] = (unsigned)s.z | (((unsigned)(ushort)rne_bf16(w.z)) << 16);
        csr[p3] = (unsigned)s.w | (((unsigned)(ushort)rne_bf16(w.w)) << 16);
    } else {
        for (int e = e0; e < NE; ++e){
            int src = ei[e], dst = ei[NE + e];
            int pos = atomicAdd(&cur[dst*NCH + chk(src)], 1);
            csr[pos] = (unsigned)src | (((unsigned)(ushort)rne_bf16(ew[e])) << 16);
        }
    }
}

// ---------- one-time prep ----------

__global__ void k_pad(const float* __restrict__ x, ushort* __restrict__ h2a){
    int idx = blockIdx.x*256 + threadIdx.x;   // 0..799999
    int n = idx >> 4, f8 = idx & 15;
    short8 v;
    if (f8 < 8){
        float4 a = *(const float4*)(x + n*FIN + f8*8);
        float4 b = *(const float4*)(x + n*FIN + f8*8 + 4);
        v[0]=rne_bf16(a.x); v[1]=rne_bf16(a.y); v[2]=rne_bf16(a.z); v[3]=rne_bf16(a.w);
        v[4]=rne_bf16(b.x); v[5]=rne_bf16(b.y); v[6]=rne_bf16(b.z); v[7]=rne_bf16(b.w);
    } else {
        v[0]=0; v[1]=0; v[2]=0; v[3]=0; v[4]=0; v[5]=0; v[6]=0; v[7]=0;
    }
    *(short8*)(h2a + idx*8) = v;
}

// fragWf[l] = bf16-frag( W_l @ w_ih^T )   [K=128][N=384]
__global__ void k_fuse(const float* __restrict__ W, const float* __restrict__ wih,
                       short* __restrict__ fwf){
    int idx = blockIdx.x*256 + threadIdx.x;   // 0..245759
    int l = idx / 49152;
    int r = idx % 49152;
    int k = r / 384, n = r % 384;
    const float4* wl = (const float4*)(W + l*16384 + k*128);
    const float4* wi = (const float4*)(wih + n*128);
    float acc = 0.f;
    #pragma unroll 8
    for (int c = 0; c < 32; ++c){
        float4 a = wl[c], b = wi[c];
        acc += a.x*b.x + a.y*b.y + a.z*b.z + a.w*b.w;
    }
    int lane = ((k>>3)&3)*16 + (n&15);
    fwf[l*49152 + (((n>>4)*4 + (k>>5))*64 + lane)*8 + (k&7)] = rne_bf16(acc);
}

__global__ void k_cvt_whh(const float* __restrict__ whh, short* __restrict__ fwhh){
    int idx = blockIdx.x*256 + threadIdx.x;   // 0..49151
    int k = idx / 384, n = idx % 384;
    float v = whh[n*128 + k];
    int lane = ((k>>3)&3)*16 + (n&15);
    fwhh[(((n>>4)*4 + (k>>5))*64 + lane)*8 + (k&7)] = rne_bf16(v);
}

__global__ void k_init_pool(unsigned* __restrict__ p){
    p[blockIdx.x*256 + threadIdx.x] = 0x007FFFFFu;   // enc(-inf)
}

// ---------- fused layer: aggregate -> dual MFMA GEMM -> register GRU ----------
// 512 threads = 8 waves, 16 nodes per block (R9-proven config, best known).
// Phase 1 walks each node's WHOLE chunk-ordered list as ONE span; chunk
// ordering makes concurrently-resident waves sweep the h-table low->high
// together -> L2 phase locality. csr stream loaded non-temporal so it does
// not evict the gather-hot h-chunk window from L2.
__global__ __launch_bounds__(512)
void k_layer(const ushort* __restrict__ h2r, ushort* __restrict__ h2w,
             const int* __restrict__ off, const unsigned* __restrict__ csr,
             const short* __restrict__ fwf, const short* __restrict__ fwhh,
             const float* __restrict__ b_ih, const float* __restrict__ b_hh,
             const int* __restrict__ batch, unsigned* __restrict__ pooled,
             int last){
    __shared__ ushort tl[16*136];             // row stride 136 ushorts (16B-aligned)
    int tid = threadIdx.x;
    int n0 = blockIdx.x * 16;
    int wave = tid >> 6, lane = tid & 63;
    int lane_lo = lane & 15, quad = lane >> 4;
    int grp = lane >> 4, fl = lane & 15;

    // ---- phase 1: pull-aggregate 2 nodes per wave into LDS (bf16) ----
    for (int sub = 0; sub < 2; ++sub){
        int node = n0 + wave*2 + sub;
        int start = __builtin_amdgcn_readfirstlane(off[node*NCH]);
        int end   = __builtin_amdgcn_readfirstlane(off[node*NCH + NCH]);
        float a0=0.f,a1=0.f,a2=0.f,a3=0.f,a4=0.f,a5=0.f,a6=0.f,a7=0.f;
        const ushort* hb = h2r + fl*8;
        for (int i = start; i < end; i += 16){
            int ii = i + grp*4;
            if (ii < end){                    // pad-4 guard (end is 4-aligned)
                uint4v c = __builtin_nontemporal_load((const uint4v*)(csr + ii));
                uint4 v0 = *(const uint4*)(hb + (c.x & 0xFFFFu)*H);
                uint4 v1 = *(const uint4*)(hb + (c.y & 0xFFFFu)*H);
                uint4 v2 = *(const uint4*)(hb + (c.z & 0xFFFFu)*H);
                uint4 v3 = *(const uint4*)(hb + (c.w & 0xFFFFu)*H);
                float w0 = bf_hi(c.x), w1 = bf_hi(c.y), w2 = bf_hi(c.z), w3 = bf_hi(c.w);
                a0 += w0*bf_lo(v0.x); a1 += w0*bf_hi(v0.x); a2 += w0*bf_lo(v0.y); a3 += w0*bf_hi(v0.y);
                a4 += w0*bf_lo(v0.z); a5 += w0*bf_hi(v0.z); a6 += w0*bf_lo(v0.w); a7 += w0*bf_hi(v0.w);
                a0 += w1*bf_lo(v1.x); a1 += w1*bf_hi(v1.x); a2 += w1*bf_lo(v1.y); a3 += w1*bf_hi(v1.y);
                a4 += w1*bf_lo(v1.z); a5 += w1*bf_hi(v1.z); a6 += w1*bf_lo(v1.w); a7 += w1*bf_hi(v1.w);
                a0 += w2*bf_lo(v2.x); a1 += w2*bf_hi(v2.x); a2 += w2*bf_lo(v2.y); a3 += w2*bf_hi(v2.y);
                a4 += w2*bf_lo(v2.z); a5 += w2*bf_hi(v2.z); a6 += w2*bf_lo(v2.w); a7 += w2*bf_hi(v2.w);
                a0 += w3*bf_lo(v3.x); a1 += w3*bf_hi(v3.x); a2 += w3*bf_lo(v3.y); a3 += w3*bf_hi(v3.y);
                a4 += w3*bf_lo(v3.z); a5 += w3*bf_hi(v3.z); a6 += w3*bf_lo(v3.w); a7 += w3*bf_hi(v3.w);
            }
        }
        // reduce across the 4 groups (each held a disjoint edge subset)
        a0 += __shfl_xor(a0,16); a1 += __shfl_xor(a1,16); a2 += __shfl_xor(a2,16); a3 += __shfl_xor(a3,16);
        a4 += __shfl_xor(a4,16); a5 += __shfl_xor(a5,16); a6 += __shfl_xor(a6,16); a7 += __shfl_xor(a7,16);
        a0 += __shfl_xor(a0,32); a1 += __shfl_xor(a1,32); a2 += __shfl_xor(a2,32); a3 += __shfl_xor(a3,32);
        a4 += __shfl_xor(a4,32); a5 += __shfl_xor(a5,32); a6 += __shfl_xor(a6,32); a7 += __shfl_xor(a7,32);
        if (lane < 16){
            short8 hbv;
            hbv[0]=rne_bf16(a0); hbv[1]=rne_bf16(a1); hbv[2]=rne_bf16(a2); hbv[3]=rne_bf16(a3);
            hbv[4]=rne_bf16(a4); hbv[5]=rne_bf16(a5); hbv[6]=rne_bf16(a6); hbv[7]=rne_bf16(a7);
            *(short8*)(tl + (wave*2 + sub)*136 + fl*8) = hbv;
        }
    }
    __syncthreads();

    // ---- phase 2: dual GEMM; wave w owns cols w*16..w*16+15 of each section ----
    f32x4 ai[3], ah[3];                       // [section]
    #pragma unroll
    for (int i = 0; i < 3; ++i){ ai[i] = (f32x4){0.f,0.f,0.f,0.f}; ah[i] = (f32x4){0.f,0.f,0.f,0.f}; }

    const ushort* arow_t = tl + lane_lo*136;
    const ushort* arow_h = h2r + (size_t)(n0 + lane_lo)*H;
    #pragma unroll
    for (int kt = 0; kt < 4; ++kt){
        short8 at  = *(const short8*)(arow_t + kt*32 + quad*8);
        short8 ahh = *(const short8*)(arow_h + kt*32 + quad*8);
        #pragma unroll
        for (int s = 0; s < 3; ++s){
            int tile = (s*8 + wave)*4 + kt;
            short8 bi = *(const short8*)(fwf  + tile*512 + lane*8);
            short8 bh = *(const short8*)(fwhh + tile*512 + lane*8);
            ai[s] = __builtin_amdgcn_mfma_f32_16x16x32_bf16(at,  bi, ai[s], 0, 0, 0);
            ah[s] = __builtin_amdgcn_mfma_f32_16x16x32_bf16(ahh, bh, ah[s], 0, 0, 0);
        }
    }

    // ---- phase 3: register-resident GRU update (+ fused pool on last) ----
    {
        int j = wave*16 + lane_lo;
        float bir = b_ih[j], biz = b_ih[128 + j], bin_ = b_ih[256 + j];
        float bhr = b_hh[j], bhz = b_hh[128 + j], bhn  = b_hh[256 + j];
        #pragma unroll
        for (int r = 0; r < 4; ++r){
            int row = n0 + quad*4 + r;
            float gir = ai[0][r] + bir, ghr = ah[0][r] + bhr;
            float giz = ai[1][r] + biz, ghz = ah[1][r] + bhz;
            float gin = ai[2][r] + bin_, ghn = ah[2][r] + bhn;
            float rr = 1.f/(1.f + __expf(-(gir + ghr)));
            float zz = 1.f/(1.f + __expf(-(giz + ghz)));
            float nn = tanhf(gin + rr*ghn);
            float ho = __uint_as_float(((unsigned)h2r[(size_t)row*H + j]) << 16);
            float hv = (1.f - zz)*nn + zz*ho;
            if (!last){
                h2w[(size_t)row*H + j] = (ushort)rne_bf16(hv);
            } else {
                int g = batch[row];
                unsigned u = __float_as_uint(hv);
                u = (u & 0x80000000u) ? ~u : (u | 0x80000000u);
                atomicMax(pooled + g*H + j, u);
            }
        }
    }
}

// ---------- tail ----------

__global__ void k_head(const unsigned* __restrict__ pooled,
                       const float* __restrict__ d1w, const float* __restrict__ d1b,
                       const float* __restrict__ d2w, const float* __restrict__ d2b,
                       float* __restrict__ out){
    __shared__ float sp[128];
    __shared__ float shid[512];
    int g = blockIdx.x, tid = threadIdx.x;
    if (tid < 128){
        unsigned u = pooled[g*H + tid];
        sp[tid] = __uint_as_float((u & 0x80000000u) ? (u ^ 0x80000000u) : ~u);
    }
    __syncthreads();
    for (int o = tid; o < 512; o += 256){
        float acc = d1b[o];
        for (int k = 0; k < H; ++k) acc += sp[k] * d1w[o*H + k];
        shid[o] = fmaxf(acc, 0.f);
    }
    __syncthreads();
    if (tid < NC){
        float acc = d2b[tid];
        for (int o = 0; o < 512; ++o) acc += shid[o] * d2w[tid*512 + o];
        out[g*NC + tid] = acc;
    }
}

extern "C" void kernel_launch(void* const* d_in, const int* in_sizes, int n_in,
                              void* d_out, int out_size, void* d_ws, size_t ws_size,
                              hipStream_t stream){
    const float* x     = (const float*)d_in[0];
    const int*   ei    = (const int*)d_in[1];
    const int*   batch = (const int*)d_in[2];
    const float* ew    = (const float*)d_in[3];
    const float* W     = (const float*)d_in[4];
    const float* wih   = (const float*)d_in[5];
    const float* whh   = (const float*)d_in[6];
    const float* bih   = (const float*)d_in[7];
    const float* bhh   = (const float*)d_in[8];
    const float* d1w   = (const float*)d_in[9];
    const float* d1b   = (const float*)d_in[10];
    const float* d2w   = (const float*)d_in[11];
    const float* d2b   = (const float*)d_in[12];
    float* out = (float*)d_out;

    float*  ws  = (float*)d_ws;
    ushort* h2a = (ushort*)(ws + OFF_H2A);
    ushort* h2b = (ushort*)(ws + OFF_H2B);
    int*    cur = (int*)(ws + OFF_CUR);      // aliases h2b (dead before layer0)
    int*    blk = (int*)(ws + OFF_BLK);      // aliases h2b (scan only)
    unsigned* pooled = (unsigned*)(ws + OFF_POOL); // aliases h2b (init after layer3)
    int*    off = (int*)(ws + OFF_OFF);
    unsigned* csr = (unsigned*)(ws + OFF_CSR);
    short*  fwf  = (short*)(ws + OFF_FWF);
    short*  fwhh = (short*)(ws + OFF_FWHH);

    hipMemsetAsync(cur, 0, (NSEG + 1)*sizeof(int), stream);
    hipMemsetAsync(csr, 0, 2265824*sizeof(unsigned), stream);   // pad slots = dummy edges
    k_hist<<<1563, 256, 0, stream>>>(ei, cur);
    k_scan1<<<SCANB, 1024, 0, stream>>>(cur, blk);
    k_scan2<<<1, 512, 0, stream>>>(blk);
    k_scan3<<<SCANB, 1024, 0, stream>>>(cur, blk, off, cur);
    k_fill<<<1563, 256, 0, stream>>>(ei, ew, cur, csr);

    k_fuse<<<960, 256, 0, stream>>>(W, wih, fwf);
    k_cvt_whh<<<192, 256, 0, stream>>>(whh, fwhh);
    k_pad<<<3125, 256, 0, stream>>>(x, h2a);

    for (int l = 0; l < NL; ++l){
        ushort* h2r = (l & 1) ? h2b : h2a;
        ushort* h2w = (l & 1) ? h2a : h2b;
        if (l == NL-1) k_init_pool<<<256, 256, 0, stream>>>(pooled);  // after last h2b read
        k_layer<<<3125, 512, 0, stream>>>(h2r, h2w, off, csr,
                                          fwf + (size_t)l*49152, fwhh, bih, bhh,
                                          batch, pooled, (l == NL-1) ? 1 : 0);
    }

    k_head<<<NG, 256, 0, stream>>>(pooled, d1w, d1b, d2w, d2b, out);
}

// Round 12
// 799.388 us; speedup vs baseline: 1.1473x; 1.0325x over previous
//
#include <hip/hip_runtime.h>
#include <hip/hip_bf16.h>

#define NN 50000
#define NE 1600000
#define FIN 64
#define H 128
#define NL 5
#define NG 512
#define NC 10
#define NCH 6          // src chunks (8192 rows = 2 MB bf16 each)
#define NSEG (NN*NCH)  // 300000 CSR segments
#define SCANB 294      // scan blocks (294*1024 >= 300001)

typedef __attribute__((ext_vector_type(8))) short short8;
typedef __attribute__((ext_vector_type(4))) float f32x4;

// ws word offsets — total 9,113,344 words (36.45 MB)
// cur/blksum/pooled ALIAS h2b (disjoint lifetimes)
#define OFF_H2A   0            // bf16 h ping (3.2M words)
#define OFF_H2B   3200000      // bf16 h pong (3.2M words)
#define OFF_CUR   3200000      // 300001 ints, transient (CSR build only)
#define OFF_BLK   3600000      // 294 ints, transient (scan block sums)
#define OFF_POOL  3200000      // 65536 unsigned, transient (after layer3)
#define OFF_OFF   6400000      // 300064 ints (padded CSR starts, persistent)
#define OFF_CSR   6700064      // 2,265,824 packed words (ushort src | bf16 w << 16)
#define OFF_FWF   8965888      // 245760 shorts (5 x 128x384 bf16 frag)
#define OFF_FWHH  9088768      // 49152 shorts -> end 9113344

__device__ __forceinline__ short rne_bf16(float f){
    unsigned u = __float_as_uint(f);
    unsigned r = (u + 0x7FFFu + ((u >> 16) & 1u)) >> 16;
    return (short)r;
}
__device__ __forceinline__ float bf_lo(unsigned v){ return __uint_as_float(v << 16); }
__device__ __forceinline__ float bf_hi(unsigned v){ return __uint_as_float(v & 0xFFFF0000u); }
__device__ __forceinline__ int chk(int s){ int c = s >> 13; return c > (NCH-1) ? (NCH-1) : c; }

// ---------- CSR build (per-(dst,chunk) sublists, chunk-ordered per dst) ----------

__global__ void k_hist(const int* __restrict__ ei, int* __restrict__ cnt){
    int e0 = (blockIdx.x*256 + threadIdx.x)*4;
    if (e0 + 3 < NE){
        int4 s = *(const int4*)(ei + e0);
        int4 d = *(const int4*)(ei + NE + e0);
        atomicAdd(&cnt[d.x*NCH + chk(s.x)], 1);
        atomicAdd(&cnt[d.y*NCH + chk(s.y)], 1);
        atomicAdd(&cnt[d.z*NCH + chk(s.z)], 1);
        atomicAdd(&cnt[d.w*NCH + chk(s.w)], 1);
    } else {
        for (int e = e0; e < NE; ++e)
            atomicAdd(&cnt[ei[NE + e]*NCH + chk(ei[e])], 1);
    }
}

// hierarchical exclusive scan of 300001 counts padded to multiples of 4
__global__ void k_scan1(const int* __restrict__ cnt, int* __restrict__ blksum){
    __shared__ int s[1024];
    int t = threadIdx.x, i = blockIdx.x*1024 + t;
    int v = (i <= NSEG) ? ((cnt[i] + 3) & ~3) : 0;
    s[t] = v; __syncthreads();
    for (int o = 512; o > 0; o >>= 1){ if (t < o) s[t] += s[t + o]; __syncthreads(); }
    if (t == 0) blksum[blockIdx.x] = s[0];
}
__global__ void k_scan2(int* __restrict__ blksum){
    __shared__ int s[512];
    int t = threadIdx.x;
    int v = (t < SCANB) ? blksum[t] : 0;
    s[t] = v; __syncthreads();
    for (int o = 1; o < 512; o <<= 1){
        int u = (t >= o) ? s[t - o] : 0; __syncthreads();
        s[t] += u; __syncthreads();
    }
    if (t < SCANB) blksum[t] = s[t] - v;     // exclusive
}
__global__ void k_scan3(const int* __restrict__ cnt, const int* __restrict__ blksum,
                        int* __restrict__ off, int* __restrict__ cur){
    __shared__ int s[1024];
    int t = threadIdx.x, i = blockIdx.x*1024 + t;
    int v = (i <= NSEG) ? ((cnt[i] + 3) & ~3) : 0;
    s[t] = v; __syncthreads();
    for (int o = 1; o < 1024; o <<= 1){
        int u = (t >= o) ? s[t - o] : 0; __syncthreads();
        s[t] += u; __syncthreads();
    }
    int e = s[t] - v + blksum[blockIdx.x];   // exclusive
    if (i <= NSEG){ off[i] = e; cur[i] = e; }
}

// packed fill: ONE 4-byte store per edge; csr pre-zeroed so pad slots are
// (src=0, w=+0.0) dummy edges. 4 independent edges per thread.
__global__ void k_fill(const int* __restrict__ ei, const float* __restrict__ ew,
                       int* __restrict__ cur, unsigned* __restrict__ csr){
    int e0 = (blockIdx.x*256 + threadIdx.x)*4;
    if (e0 + 3 < NE){
        int4   s = *(const int4*)(ei + e0);
        int4   d = *(const int4*)(ei + NE + e0);
        float4 w = *(const float4*)(ew + e0);
        int p0 = atomicAdd(&cur[d.x*NCH + chk(s.x)], 1);
        int p1 = atomicAdd(&cur[d.y*NCH + chk(s.y)], 1);
        int p2 = atomicAdd(&cur[d.z*NCH + chk(s.z)], 1);
        int p3 = atomicAdd(&cur[d.w*NCH + chk(s.w)], 1);
        csr[p0] = (unsigned)s.x | (((unsigned)(ushort)rne_bf16(w.x)) << 16);
        csr[p1] = (unsigned)s.y | (((unsigned)(ushort)rne_bf16(w.y)) << 16);
        csr[p2] = (unsigned)s.z | (((unsigned)(ushort)rne_bf16(w.z)) << 16);
        csr[p3] = (unsigned)s.w | (((unsigned)(ushort)rne_bf16(w.w)) << 16);
    } else {
        for (int e = e0; e < NE; ++e){
            int src = ei[e], dst = ei[NE + e];
            int pos = atomicAdd(&cur[dst*NCH + chk(src)], 1);
            csr[pos] = (unsigned)src | (((unsigned)(ushort)rne_bf16(ew[e])) << 16);
        }
    }
}

// ---------- one-time prep ----------

__global__ void k_pad(const float* __restrict__ x, ushort* __restrict__ h2a){
    int idx = blockIdx.x*256 + threadIdx.x;   // 0..799999
    int n = idx >> 4, f8 = idx & 15;
    short8 v;
    if (f8 < 8){
        float4 a = *(const float4*)(x + n*FIN + f8*8);
        float4 b = *(const float4*)(x + n*FIN + f8*8 + 4);
        v[0]=rne_bf16(a.x); v[1]=rne_bf16(a.y); v[2]=rne_bf16(a.z); v[3]=rne_bf16(a.w);
        v[4]=rne_bf16(b.x); v[5]=rne_bf16(b.y); v[6]=rne_bf16(b.z); v[7]=rne_bf16(b.w);
    } else {
        v[0]=0; v[1]=0; v[2]=0; v[3]=0; v[4]=0; v[5]=0; v[6]=0; v[7]=0;
    }
    *(short8*)(h2a + idx*8) = v;
}

// fragWf[l] = bf16-frag( W_l @ w_ih^T )   [K=128][N=384]
__global__ void k_fuse(const float* __restrict__ W, const float* __restrict__ wih,
                       short* __restrict__ fwf){
    int idx = blockIdx.x*256 + threadIdx.x;   // 0..245759
    int l = idx / 49152;
    int r = idx % 49152;
    int k = r / 384, n = r % 384;
    const float4* wl = (const float4*)(W + l*16384 + k*128);
    const float4* wi = (const float4*)(wih + n*128);
    float acc = 0.f;
    #pragma unroll 8
    for (int c = 0; c < 32; ++c){
        float4 a = wl[c], b = wi[c];
        acc += a.x*b.x + a.y*b.y + a.z*b.z + a.w*b.w;
    }
    int lane = ((k>>3)&3)*16 + (n&15);
    fwf[l*49152 + (((n>>4)*4 + (k>>5))*64 + lane)*8 + (k&7)] = rne_bf16(acc);
}

__global__ void k_cvt_whh(const float* __restrict__ whh, short* __restrict__ fwhh){
    int idx = blockIdx.x*256 + threadIdx.x;   // 0..49151
    int k = idx / 384, n = idx % 384;
    float v = whh[n*128 + k];
    int lane = ((k>>3)&3)*16 + (n&15);
    fwhh[(((n>>4)*4 + (k>>5))*64 + lane)*8 + (k&7)] = rne_bf16(v);
}

__global__ void k_init_pool(unsigned* __restrict__ p){
    p[blockIdx.x*256 + threadIdx.x] = 0x007FFFFFu;   // enc(-inf)
}

// ---------- fused layer: aggregate -> dual MFMA GEMM -> register GRU ----------
// 512 threads = 8 waves, 16 nodes per block (R9-proven config, best known).
// Phase 1 walks each node's WHOLE chunk-ordered list as ONE span; chunk
// ordering makes concurrently-resident waves sweep the h-table low->high
// together -> L2 phase locality.
__global__ __launch_bounds__(512)
void k_layer(const ushort* __restrict__ h2r, ushort* __restrict__ h2w,
             const int* __restrict__ off, const unsigned* __restrict__ csr,
             const short* __restrict__ fwf, const short* __restrict__ fwhh,
             const float* __restrict__ b_ih, const float* __restrict__ b_hh,
             const int* __restrict__ batch, unsigned* __restrict__ pooled,
             int last){
    __shared__ ushort tl[16*136];             // row stride 136 ushorts (16B-aligned)
    int tid = threadIdx.x;
    int n0 = blockIdx.x * 16;
    int wave = tid >> 6, lane = tid & 63;
    int lane_lo = lane & 15, quad = lane >> 4;
    int grp = lane >> 4, fl = lane & 15;

    // ---- phase 1: pull-aggregate 2 nodes per wave into LDS (bf16) ----
    for (int sub = 0; sub < 2; ++sub){
        int node = n0 + wave*2 + sub;
        int start = __builtin_amdgcn_readfirstlane(off[node*NCH]);
        int end   = __builtin_amdgcn_readfirstlane(off[node*NCH + NCH]);
        float a0=0.f,a1=0.f,a2=0.f,a3=0.f,a4=0.f,a5=0.f,a6=0.f,a7=0.f;
        const ushort* hb = h2r + fl*8;
        for (int i = start; i < end; i += 16){
            int ii = i + grp*4;
            if (ii < end){                    // pad-4 guard (end is 4-aligned)
                uint4 c = *(const uint4*)(csr + ii);
                uint4 v0 = *(const uint4*)(hb + (c.x & 0xFFFFu)*H);
                uint4 v1 = *(const uint4*)(hb + (c.y & 0xFFFFu)*H);
                uint4 v2 = *(const uint4*)(hb + (c.z & 0xFFFFu)*H);
                uint4 v3 = *(const uint4*)(hb + (c.w & 0xFFFFu)*H);
                float w0 = bf_hi(c.x), w1 = bf_hi(c.y), w2 = bf_hi(c.z), w3 = bf_hi(c.w);
                a0 += w0*bf_lo(v0.x); a1 += w0*bf_hi(v0.x); a2 += w0*bf_lo(v0.y); a3 += w0*bf_hi(v0.y);
                a4 += w0*bf_lo(v0.z); a5 += w0*bf_hi(v0.z); a6 += w0*bf_lo(v0.w); a7 += w0*bf_hi(v0.w);
                a0 += w1*bf_lo(v1.x); a1 += w1*bf_hi(v1.x); a2 += w1*bf_lo(v1.y); a3 += w1*bf_hi(v1.y);
                a4 += w1*bf_lo(v1.z); a5 += w1*bf_hi(v1.z); a6 += w1*bf_lo(v1.w); a7 += w1*bf_hi(v1.w);
                a0 += w2*bf_lo(v2.x); a1 += w2*bf_hi(v2.x); a2 += w2*bf_lo(v2.y); a3 += w2*bf_hi(v2.y);
                a4 += w2*bf_lo(v2.z); a5 += w2*bf_hi(v2.z); a6 += w2*bf_lo(v2.w); a7 += w2*bf_hi(v2.w);
                a0 += w3*bf_lo(v3.x); a1 += w3*bf_hi(v3.x); a2 += w3*bf_lo(v3.y); a3 += w3*bf_hi(v3.y);
                a4 += w3*bf_lo(v3.z); a5 += w3*bf_hi(v3.z); a6 += w3*bf_lo(v3.w); a7 += w3*bf_hi(v3.w);
            }
        }
        // reduce across the 4 groups (each held a disjoint edge subset)
        a0 += __shfl_xor(a0,16); a1 += __shfl_xor(a1,16); a2 += __shfl_xor(a2,16); a3 += __shfl_xor(a3,16);
        a4 += __shfl_xor(a4,16); a5 += __shfl_xor(a5,16); a6 += __shfl_xor(a6,16); a7 += __shfl_xor(a7,16);
        a0 += __shfl_xor(a0,32); a1 += __shfl_xor(a1,32); a2 += __shfl_xor(a2,32); a3 += __shfl_xor(a3,32);
        a4 += __shfl_xor(a4,32); a5 += __shfl_xor(a5,32); a6 += __shfl_xor(a6,32); a7 += __shfl_xor(a7,32);
        if (lane < 16){
            short8 hbv;
            hbv[0]=rne_bf16(a0); hbv[1]=rne_bf16(a1); hbv[2]=rne_bf16(a2); hbv[3]=rne_bf16(a3);
            hbv[4]=rne_bf16(a4); hbv[5]=rne_bf16(a5); hbv[6]=rne_bf16(a6); hbv[7]=rne_bf16(a7);
            *(short8*)(tl + (wave*2 + sub)*136 + fl*8) = hbv;
        }
    }
    __syncthreads();

    // ---- phase 2: dual GEMM; wave w owns cols w*16..w*16+15 of each section ----
    f32x4 ai[3], ah[3];                       // [section]
    #pragma unroll
    for (int i = 0; i < 3; ++i){ ai[i] = (f32x4){0.f,0.f,0.f,0.f}; ah[i] = (f32x4){0.f,0.f,0.f,0.f}; }

    const ushort* arow_t = tl + lane_lo*136;
    const ushort* arow_h = h2r + (size_t)(n0 + lane_lo)*H;
    #pragma unroll
    for (int kt = 0; kt < 4; ++kt){
        short8 at  = *(const short8*)(arow_t + kt*32 + quad*8);
        short8 ahh = *(const short8*)(arow_h + kt*32 + quad*8);
        #pragma unroll
        for (int s = 0; s < 3; ++s){
            int tile = (s*8 + wave)*4 + kt;
            short8 bi = *(const short8*)(fwf  + tile*512 + lane*8);
            short8 bh = *(const short8*)(fwhh + tile*512 + lane*8);
            ai[s] = __builtin_amdgcn_mfma_f32_16x16x32_bf16(at,  bi, ai[s], 0, 0, 0);
            ah[s] = __builtin_amdgcn_mfma_f32_16x16x32_bf16(ahh, bh, ah[s], 0, 0, 0);
        }
    }

    // ---- phase 3: register-resident GRU update (+ fused pool on last) ----
    {
        int j = wave*16 + lane_lo;
        float bir = b_ih[j], biz = b_ih[128 + j], bin_ = b_ih[256 + j];
        float bhr = b_hh[j], bhz = b_hh[128 + j], bhn  = b_hh[256 + j];
        #pragma unroll
        for (int r = 0; r < 4; ++r){
            int row = n0 + quad*4 + r;
            float gir = ai[0][r] + bir, ghr = ah[0][r] + bhr;
            float giz = ai[1][r] + biz, ghz = ah[1][r] + bhz;
            float gin = ai[2][r] + bin_, ghn = ah[2][r] + bhn;
            float rr = 1.f/(1.f + __expf(-(gir + ghr)));
            float zz = 1.f/(1.f + __expf(-(giz + ghz)));
            float nn = tanhf(gin + rr*ghn);
            float ho = __uint_as_float(((unsigned)h2r[(size_t)row*H + j]) << 16);
            float hv = (1.f - zz)*nn + zz*ho;
            if (!last){
                h2w[(size_t)row*H + j] = (ushort)rne_bf16(hv);
            } else {
                int g = batch[row];
                unsigned u = __float_as_uint(hv);
                u = (u & 0x80000000u) ? ~u : (u | 0x80000000u);
                atomicMax(pooled + g*H + j, u);
            }
        }
    }
}

// ---------- tail ----------

__global__ void k_head(const unsigned* __restrict__ pooled,
                       const float* __restrict__ d1w, const float* __restrict__ d1b,
                       const float* __restrict__ d2w, const float* __restrict__ d2b,
                       float* __restrict__ out){
    __shared__ float sp[128];
    __shared__ float shid[512];
    int g = blockIdx.x, tid = threadIdx.x;
    if (tid < 128){
        unsigned u = pooled[g*H + tid];
        sp[tid] = __uint_as_float((u & 0x80000000u) ? (u ^ 0x80000000u) : ~u);
    }
    __syncthreads();
    for (int o = tid; o < 512; o += 256){
        float acc = d1b[o];
        for (int k = 0; k < H; ++k) acc += sp[k] * d1w[o*H + k];
        shid[o] = fmaxf(acc, 0.f);
    }
    __syncthreads();
    if (tid < NC){
        float acc = d2b[tid];
        for (int o = 0; o < 512; ++o) acc += shid[o] * d2w[tid*512 + o];
        out[g*NC + tid] = acc;
    }
}

extern "C" void kernel_launch(void* const* d_in, const int* in_sizes, int n_in,
                              void* d_out, int out_size, void* d_ws, size_t ws_size,
                              hipStream_t stream){
    const float* x     = (const float*)d_in[0];
    const int*   ei    = (const int*)d_in[1];
    const int*   batch = (const int*)d_in[2];
    const float* ew    = (const float*)d_in[3];
    const float* W     = (const float*)d_in[4];
    const float* wih   = (const float*)d_in[5];
    const float* whh   = (const float*)d_in[6];
    const float* bih   = (const float*)d_in[7];
    const float* bhh   = (const float*)d_in[8];
    const float* d1w   = (const float*)d_in[9];
    const float* d1b   = (const float*)d_in[10];
    const float* d2w   = (const float*)d_in[11];
    const float* d2b   = (const float*)d_in[12];
    float* out = (float*)d_out;

    float*  ws  = (float*)d_ws;
    ushort* h2a = (ushort*)(ws + OFF_H2A);
    ushort* h2b = (ushort*)(ws + OFF_H2B);
    int*    cur = (int*)(ws + OFF_CUR);      // aliases h2b (dead before layer0)
    int*    blk = (int*)(ws + OFF_BLK);      // aliases h2b (scan only)
    unsigned* pooled = (unsigned*)(ws + OFF_POOL); // aliases h2b (init after layer3)
    int*    off = (int*)(ws + OFF_OFF);
    unsigned* csr = (unsigned*)(ws + OFF_CSR);
    short*  fwf  = (short*)(ws + OFF_FWF);
    short*  fwhh = (short*)(ws + OFF_FWHH);

    hipMemsetAsync(cur, 0, (NSEG + 1)*sizeof(int), stream);
    hipMemsetAsync(csr, 0, 2265824*sizeof(unsigned), stream);   // pad slots = dummy edges
    k_hist<<<1563, 256, 0, stream>>>(ei, cur);
    k_scan1<<<SCANB, 1024, 0, stream>>>(cur, blk);
    k_scan2<<<1, 512, 0, stream>>>(blk);
    k_scan3<<<SCANB, 1024, 0, stream>>>(cur, blk, off, cur);
    k_fill<<<1563, 256, 0, stream>>>(ei, ew, cur, csr);

    k_fuse<<<960, 256, 0, stream>>>(W, wih, fwf);
    k_cvt_whh<<<192, 256, 0, stream>>>(whh, fwhh);
    k_pad<<<3125, 256, 0, stream>>>(x, h2a);

    for (int l = 0; l < NL; ++l){
        ushort* h2r = (l & 1) ? h2b : h2a;
        ushort* h2w = (l & 1) ? h2a : h2b;
        if (l == NL-1) k_init_pool<<<256, 256, 0, stream>>>(pooled);  // after last h2b read
        k_layer<<<3125, 512, 0, stream>>>(h2r, h2w, off, csr,
                                          fwf + (size_t)l*49152, fwhh, bih, bhh,
                                          batch, pooled, (l == NL-1) ? 1 : 0);
    }

    k_head<<<NG, 256, 0, stream>>>(pooled, d1w, d1b, d2w, d2b, out);
}

// Round 13
// 790.845 us; speedup vs baseline: 1.1597x; 1.0108x over previous
//
#include <hip/hip_runtime.h>
#include <hip/hip_bf16.h>

#define NN 50000
#define NE 1600000
#define FIN 64
#define H 128
#define NL 5
#define NG 512
#define NC 10
#define NCH 6          // src chunks (8192 rows = 2 MB bf16 each)
#define NSEG (NN*NCH)  // 300000 CSR segments
#define SCANB 49       // node-scan blocks (49*1024 >= 50001)

typedef __attribute__((ext_vector_type(8))) short short8;
typedef __attribute__((ext_vector_type(4))) float f32x4;

// ws word offsets — total 9,113,344 words (36.45 MB)
// cur/blksum/pooled ALIAS h2b (disjoint lifetimes)
#define OFF_H2A   0            // bf16 h ping (3.2M words)
#define OFF_H2B   3200000      // bf16 h pong (3.2M words)
#define OFF_CUR   3200000      // 300001 ints, transient (CSR build only)
#define OFF_BLK   3600000      // 49 ints, transient (scan block sums)
#define OFF_POOL  3200000      // 65536 unsigned, transient (after layer3)
#define OFF_OFF   6400000      // 300064 ints (padded CSR starts, persistent)
#define OFF_CSR   6700064      // csr: max 1.75M used (2.26M reserved)
#define OFF_FWF   8965888      // 245760 shorts (5 x 128x384 bf16 frag)
#define OFF_FWHH  9088768      // 49152 shorts -> end 9113344

__device__ __forceinline__ short rne_bf16(float f){
    unsigned u = __float_as_uint(f);
    unsigned r = (u + 0x7FFFu + ((u >> 16) & 1u)) >> 16;
    return (short)r;
}
__device__ __forceinline__ float bf_lo(unsigned v){ return __uint_as_float(v << 16); }
__device__ __forceinline__ float bf_hi(unsigned v){ return __uint_as_float(v & 0xFFFF0000u); }
__device__ __forceinline__ int chk(int s){ int c = s >> 13; return c > (NCH-1) ? (NCH-1) : c; }

// ---------- CSR build: per-(dst,chunk) sublists packed contiguously per dst,
// padding applied per NODE (round4 of total) -> ~75K dummies vs 450K per-seg ----------

__global__ void k_hist(const int* __restrict__ ei, int* __restrict__ cnt){
    int e0 = (blockIdx.x*256 + threadIdx.x)*4;
    if (e0 + 3 < NE){
        int4 s = *(const int4*)(ei + e0);
        int4 d = *(const int4*)(ei + NE + e0);
        atomicAdd(&cnt[d.x*NCH + chk(s.x)], 1);
        atomicAdd(&cnt[d.y*NCH + chk(s.y)], 1);
        atomicAdd(&cnt[d.z*NCH + chk(s.z)], 1);
        atomicAdd(&cnt[d.w*NCH + chk(s.w)], 1);
    } else {
        for (int e = e0; e < NE; ++e)
            atomicAdd(&cnt[ei[NE + e]*NCH + chk(ei[e])], 1);
    }
}

// pass 1: per-node padded totals -> block sums (value = round4(sum of 6 chunk counts))
__global__ void k_nscan1(const int* __restrict__ cnt, int* __restrict__ blksum){
    __shared__ int s[1024];
    int t = threadIdx.x, n = blockIdx.x*1024 + t;
    int v = 0;
    if (n < NN){
        int tot = 0;
        #pragma unroll
        for (int c = 0; c < NCH; ++c) tot += cnt[n*NCH + c];
        v = (tot + 3) & ~3;
    }
    s[t] = v; __syncthreads();
    for (int o = 512; o > 0; o >>= 1){ if (t < o) s[t] += s[t + o]; __syncthreads(); }
    if (t == 0) blksum[blockIdx.x] = s[0];
}

// pass 2: exclusive scan of SCANB block sums
__global__ void k_scan2(int* __restrict__ blksum){
    __shared__ int s[512];
    int t = threadIdx.x;
    int v = (t < SCANB) ? blksum[t] : 0;
    s[t] = v; __syncthreads();
    for (int o = 1; o < 512; o <<= 1){
        int u = (t >= o) ? s[t - o] : 0; __syncthreads();
        s[t] += u; __syncthreads();
    }
    if (t < SCANB) blksum[t] = s[t] - v;     // exclusive
}

// pass 3: per-node exclusive base; write 6 intra-node chunk offsets (packed,
// unpadded) to off[] and cur[]; node NN's slot writes the sentinel.
__global__ void k_nscan3(int* __restrict__ cnt_cur, const int* __restrict__ blksum,
                         int* __restrict__ off){
    __shared__ int s[1024];
    int t = threadIdx.x, n = blockIdx.x*1024 + t;
    int cc[NCH]; int v = 0;
    if (n < NN){
        int tot = 0;
        #pragma unroll
        for (int c = 0; c < NCH; ++c){ cc[c] = cnt_cur[n*NCH + c]; tot += cc[c]; }
        v = (tot + 3) & ~3;
    }
    s[t] = v; __syncthreads();
    for (int o = 1; o < 1024; o <<= 1){
        int u = (t >= o) ? s[t - o] : 0; __syncthreads();
        s[t] += u; __syncthreads();
    }
    int base = s[t] - v + blksum[blockIdx.x];   // exclusive
    if (n < NN){
        int run = base;
        #pragma unroll
        for (int c = 0; c < NCH; ++c){
            off[n*NCH + c] = run;
            cnt_cur[n*NCH + c] = run;
            run += cc[c];
        }
    } else if (n == NN){
        off[NSEG] = base;                       // total (4-aligned)
    }
}

// packed fill: ONE 4-byte store per edge; csr pre-zeroed so pad slots are
// (src=0, w=+0.0) dummy edges. 4 independent edges per thread.
__global__ void k_fill(const int* __restrict__ ei, const float* __restrict__ ew,
                       int* __restrict__ cur, unsigned* __restrict__ csr){
    int e0 = (blockIdx.x*256 + threadIdx.x)*4;
    if (e0 + 3 < NE){
        int4   s = *(const int4*)(ei + e0);
        int4   d = *(const int4*)(ei + NE + e0);
        float4 w = *(const float4*)(ew + e0);
        int p0 = atomicAdd(&cur[d.x*NCH + chk(s.x)], 1);
        int p1 = atomicAdd(&cur[d.y*NCH + chk(s.y)], 1);
        int p2 = atomicAdd(&cur[d.z*NCH + chk(s.z)], 1);
        int p3 = atomicAdd(&cur[d.w*NCH + chk(s.w)], 1);
        csr[p0] = (unsigned)s.x | (((unsigned)(ushort)rne_bf16(w.x)) << 16);
        csr[p1] = (unsigned)s.y | (((unsigned)(ushort)rne_bf16(w.y)) << 16);
        csr[p2] = (unsigned)s.z | (((unsigned)(ushort)rne_bf16(w.z)) << 16);
        csr[p3] = (unsigned)s.w | (((unsigned)(ushort)rne_bf16(w.w)) << 16);
    } else {
        for (int e = e0; e < NE; ++e){
            int src = ei[e], dst = ei[NE + e];
            int pos = atomicAdd(&cur[dst*NCH + chk(src)], 1);
            csr[pos] = (unsigned)src | (((unsigned)(ushort)rne_bf16(ew[e])) << 16);
        }
    }
}

// ---------- one-time prep ----------

__global__ void k_pad(const float* __restrict__ x, ushort* __restrict__ h2a){
    int idx = blockIdx.x*256 + threadIdx.x;   // 0..799999
    int n = idx >> 4, f8 = idx & 15;
    short8 v;
    if (f8 < 8){
        float4 a = *(const float4*)(x + n*FIN + f8*8);
        float4 b = *(const float4*)(x + n*FIN + f8*8 + 4);
        v[0]=rne_bf16(a.x); v[1]=rne_bf16(a.y); v[2]=rne_bf16(a.z); v[3]=rne_bf16(a.w);
        v[4]=rne_bf16(b.x); v[5]=rne_bf16(b.y); v[6]=rne_bf16(b.z); v[7]=rne_bf16(b.w);
    } else {
        v[0]=0; v[1]=0; v[2]=0; v[3]=0; v[4]=0; v[5]=0; v[6]=0; v[7]=0;
    }
    *(short8*)(h2a + idx*8) = v;
}

// fragWf[l] = bf16-frag( W_l @ w_ih^T )   [K=128][N=384]
__global__ void k_fuse(const float* __restrict__ W, const float* __restrict__ wih,
                       short* __restrict__ fwf){
    int idx = blockIdx.x*256 + threadIdx.x;   // 0..245759
    int l = idx / 49152;
    int r = idx % 49152;
    int k = r / 384, n = r % 384;
    const float4* wl = (const float4*)(W + l*16384 + k*128);
    const float4* wi = (const float4*)(wih + n*128);
    float acc = 0.f;
    #pragma unroll 8
    for (int c = 0; c < 32; ++c){
        float4 a = wl[c], b = wi[c];
        acc += a.x*b.x + a.y*b.y + a.z*b.z + a.w*b.w;
    }
    int lane = ((k>>3)&3)*16 + (n&15);
    fwf[l*49152 + (((n>>4)*4 + (k>>5))*64 + lane)*8 + (k&7)] = rne_bf16(acc);
}

__global__ void k_cvt_whh(const float* __restrict__ whh, short* __restrict__ fwhh){
    int idx = blockIdx.x*256 + threadIdx.x;   // 0..49151
    int k = idx / 384, n = idx % 384;
    float v = whh[n*128 + k];
    int lane = ((k>>3)&3)*16 + (n&15);
    fwhh[(((n>>4)*4 + (k>>5))*64 + lane)*8 + (k&7)] = rne_bf16(v);
}

__global__ void k_init_pool(unsigned* __restrict__ p){
    p[blockIdx.x*256 + threadIdx.x] = 0x007FFFFFu;   // enc(-inf)
}

// ---------- fused layer: aggregate -> dual MFMA GEMM -> register GRU ----------
// 512 threads = 8 waves, 16 nodes per block (R9-proven config).
// Phase 1 walks each node's WHOLE chunk-ordered list as ONE span; chunk
// ordering gives L2 phase locality; per-node pad-4 keeps dummy edges ~4.5%.
__global__ __launch_bounds__(512)
void k_layer(const ushort* __restrict__ h2r, ushort* __restrict__ h2w,
             const int* __restrict__ off, const unsigned* __restrict__ csr,
             const short* __restrict__ fwf, const short* __restrict__ fwhh,
             const float* __restrict__ b_ih, const float* __restrict__ b_hh,
             const int* __restrict__ batch, unsigned* __restrict__ pooled,
             int last){
    __shared__ ushort tl[16*136];             // row stride 136 ushorts (16B-aligned)
    int tid = threadIdx.x;
    int n0 = blockIdx.x * 16;
    int wave = tid >> 6, lane = tid & 63;
    int lane_lo = lane & 15, quad = lane >> 4;
    int grp = lane >> 4, fl = lane & 15;

    // ---- phase 1: pull-aggregate 2 nodes per wave into LDS (bf16) ----
    for (int sub = 0; sub < 2; ++sub){
        int node = n0 + wave*2 + sub;
        int start = __builtin_amdgcn_readfirstlane(off[node*NCH]);
        int end   = __builtin_amdgcn_readfirstlane(off[node*NCH + NCH]);
        float a0=0.f,a1=0.f,a2=0.f,a3=0.f,a4=0.f,a5=0.f,a6=0.f,a7=0.f;
        const ushort* hb = h2r + fl*8;
        for (int i = start; i < end; i += 16){
            int ii = i + grp*4;
            if (ii < end){                    // pad-4 guard (end is 4-aligned)
                uint4 c = *(const uint4*)(csr + ii);
                uint4 v0 = *(const uint4*)(hb + (c.x & 0xFFFFu)*H);
                uint4 v1 = *(const uint4*)(hb + (c.y & 0xFFFFu)*H);
                uint4 v2 = *(const uint4*)(hb + (c.z & 0xFFFFu)*H);
                uint4 v3 = *(const uint4*)(hb + (c.w & 0xFFFFu)*H);
                float w0 = bf_hi(c.x), w1 = bf_hi(c.y), w2 = bf_hi(c.z), w3 = bf_hi(c.w);
                a0 += w0*bf_lo(v0.x); a1 += w0*bf_hi(v0.x); a2 += w0*bf_lo(v0.y); a3 += w0*bf_hi(v0.y);
                a4 += w0*bf_lo(v0.z); a5 += w0*bf_hi(v0.z); a6 += w0*bf_lo(v0.w); a7 += w0*bf_hi(v0.w);
                a0 += w1*bf_lo(v1.x); a1 += w1*bf_hi(v1.x); a2 += w1*bf_lo(v1.y); a3 += w1*bf_hi(v1.y);
                a4 += w1*bf_lo(v1.z); a5 += w1*bf_hi(v1.z); a6 += w1*bf_lo(v1.w); a7 += w1*bf_hi(v1.w);
                a0 += w2*bf_lo(v2.x); a1 += w2*bf_hi(v2.x); a2 += w2*bf_lo(v2.y); a3 += w2*bf_hi(v2.y);
                a4 += w2*bf_lo(v2.z); a5 += w2*bf_hi(v2.z); a6 += w2*bf_lo(v2.w); a7 += w2*bf_hi(v2.w);
                a0 += w3*bf_lo(v3.x); a1 += w3*bf_hi(v3.x); a2 += w3*bf_lo(v3.y); a3 += w3*bf_hi(v3.y);
                a4 += w3*bf_lo(v3.z); a5 += w3*bf_hi(v3.z); a6 += w3*bf_lo(v3.w); a7 += w3*bf_hi(v3.w);
            }
        }
        // reduce across the 4 groups (each held a disjoint edge subset)
        a0 += __shfl_xor(a0,16); a1 += __shfl_xor(a1,16); a2 += __shfl_xor(a2,16); a3 += __shfl_xor(a3,16);
        a4 += __shfl_xor(a4,16); a5 += __shfl_xor(a5,16); a6 += __shfl_xor(a6,16); a7 += __shfl_xor(a7,16);
        a0 += __shfl_xor(a0,32); a1 += __shfl_xor(a1,32); a2 += __shfl_xor(a2,32); a3 += __shfl_xor(a3,32);
        a4 += __shfl_xor(a4,32); a5 += __shfl_xor(a5,32); a6 += __shfl_xor(a6,32); a7 += __shfl_xor(a7,32);
        if (lane < 16){
            short8 hbv;
            hbv[0]=rne_bf16(a0); hbv[1]=rne_bf16(a1); hbv[2]=rne_bf16(a2); hbv[3]=rne_bf16(a3);
            hbv[4]=rne_bf16(a4); hbv[5]=rne_bf16(a5); hbv[6]=rne_bf16(a6); hbv[7]=rne_bf16(a7);
            *(short8*)(tl + (wave*2 + sub)*136 + fl*8) = hbv;
        }
    }
    __syncthreads();

    // ---- phase 2: dual GEMM; wave w owns cols w*16..w*16+15 of each section ----
    f32x4 ai[3], ah[3];                       // [section]
    #pragma unroll
    for (int i = 0; i < 3; ++i){ ai[i] = (f32x4){0.f,0.f,0.f,0.f}; ah[i] = (f32x4){0.f,0.f,0.f,0.f}; }

    const ushort* arow_t = tl + lane_lo*136;
    const ushort* arow_h = h2r + (size_t)(n0 + lane_lo)*H;
    #pragma unroll
    for (int kt = 0; kt < 4; ++kt){
        short8 at  = *(const short8*)(arow_t + kt*32 + quad*8);
        short8 ahh = *(const short8*)(arow_h + kt*32 + quad*8);
        #pragma unroll
        for (int s = 0; s < 3; ++s){
            int tile = (s*8 + wave)*4 + kt;
            short8 bi = *(const short8*)(fwf  + tile*512 + lane*8);
            short8 bh = *(const short8*)(fwhh + tile*512 + lane*8);
            ai[s] = __builtin_amdgcn_mfma_f32_16x16x32_bf16(at,  bi, ai[s], 0, 0, 0);
            ah[s] = __builtin_amdgcn_mfma_f32_16x16x32_bf16(ahh, bh, ah[s], 0, 0, 0);
        }
    }

    // ---- phase 3: register-resident GRU update (+ fused pool on last) ----
    {
        int j = wave*16 + lane_lo;
        float bir = b_ih[j], biz = b_ih[128 + j], bin_ = b_ih[256 + j];
        float bhr = b_hh[j], bhz = b_hh[128 + j], bhn  = b_hh[256 + j];
        #pragma unroll
        for (int r = 0; r < 4; ++r){
            int row = n0 + quad*4 + r;
            float gir = ai[0][r] + bir, ghr = ah[0][r] + bhr;
            float giz = ai[1][r] + biz, ghz = ah[1][r] + bhz;
            float gin = ai[2][r] + bin_, ghn = ah[2][r] + bhn;
            float rr = 1.f/(1.f + __expf(-(gir + ghr)));
            float zz = 1.f/(1.f + __expf(-(giz + ghz)));
            float nn = tanhf(gin + rr*ghn);
            float ho = __uint_as_float(((unsigned)h2r[(size_t)row*H + j]) << 16);
            float hv = (1.f - zz)*nn + zz*ho;
            if (!last){
                h2w[(size_t)row*H + j] = (ushort)rne_bf16(hv);
            } else {
                int g = batch[row];
                unsigned u = __float_as_uint(hv);
                u = (u & 0x80000000u) ? ~u : (u | 0x80000000u);
                atomicMax(pooled + g*H + j, u);
            }
        }
    }
}

// ---------- tail ----------

__global__ void k_head(const unsigned* __restrict__ pooled,
                       const float* __restrict__ d1w, const float* __restrict__ d1b,
                       const float* __restrict__ d2w, const float* __restrict__ d2b,
                       float* __restrict__ out){
    __shared__ float sp[128];
    __shared__ float shid[512];
    int g = blockIdx.x, tid = threadIdx.x;
    if (tid < 128){
        unsigned u = pooled[g*H + tid];
        sp[tid] = __uint_as_float((u & 0x80000000u) ? (u ^ 0x80000000u) : ~u);
    }
    __syncthreads();
    for (int o = tid; o < 512; o += 256){
        float acc = d1b[o];
        for (int k = 0; k < H; ++k) acc += sp[k] * d1w[o*H + k];
        shid[o] = fmaxf(acc, 0.f);
    }
    __syncthreads();
    if (tid < NC){
        float acc = d2b[tid];
        for (int o = 0; o < 512; ++o) acc += shid[o] * d2w[tid*512 + o];
        out[g*NC + tid] = acc;
    }
}

extern "C" void kernel_launch(void* const* d_in, const int* in_sizes, int n_in,
                              void* d_out, int out_size, void* d_ws, size_t ws_size,
                              hipStream_t stream){
    const float* x     = (const float*)d_in[0];
    const int*   ei    = (const int*)d_in[1];
    const int*   batch = (const int*)d_in[2];
    const float* ew    = (const float*)d_in[3];
    const float* W     = (const float*)d_in[4];
    const float* wih   = (const float*)d_in[5];
    const float* whh   = (const float*)d_in[6];
    const float* bih   = (const float*)d_in[7];
    const float* bhh   = (const float*)d_in[8];
    const float* d1w   = (const float*)d_in[9];
    const float* d1b   = (const float*)d_in[10];
    const float* d2w   = (const float*)d_in[11];
    const float* d2b   = (const float*)d_in[12];
    float* out = (float*)d_out;

    float*  ws  = (float*)d_ws;
    ushort* h2a = (ushort*)(ws + OFF_H2A);
    ushort* h2b = (ushort*)(ws + OFF_H2B);
    int*    cur = (int*)(ws + OFF_CUR);      // aliases h2b (dead before layer0)
    int*    blk = (int*)(ws + OFF_BLK);      // aliases h2b (scan only)
    unsigned* pooled = (unsigned*)(ws + OFF_POOL); // aliases h2b (init after layer3)
    int*    off = (int*)(ws + OFF_OFF);
    unsigned* csr = (unsigned*)(ws + OFF_CSR);
    short*  fwf  = (short*)(ws + OFF_FWF);
    short*  fwhh = (short*)(ws + OFF_FWHH);

    hipMemsetAsync(cur, 0, (NSEG + 1)*sizeof(int), stream);
    hipMemsetAsync(csr, 0, 1750000*sizeof(unsigned), stream);   // max padded total = 1.6M+150K
    k_hist<<<1563, 256, 0, stream>>>(ei, cur);
    k_nscan1<<<SCANB, 1024, 0, stream>>>(cur, blk);
    k_scan2<<<1, 512, 0, stream>>>(blk);
    k_nscan3<<<SCANB, 1024, 0, stream>>>(cur, blk, off);
    k_fill<<<1563, 256, 0, stream>>>(ei, ew, cur, csr);

    k_fuse<<<960, 256, 0, stream>>>(W, wih, fwf);
    k_cvt_whh<<<192, 256, 0, stream>>>(whh, fwhh);
    k_pad<<<3125, 256, 0, stream>>>(x, h2a);

    for (int l = 0; l < NL; ++l){
        ushort* h2r = (l & 1) ? h2b : h2a;
        ushort* h2w = (l & 1) ? h2a : h2b;
        if (l == NL-1) k_init_pool<<<256, 256, 0, stream>>>(pooled);  // after last h2b read
        k_layer<<<3125, 512, 0, stream>>>(h2r, h2w, off, csr,
                                          fwf + (size_t)l*49152, fwhh, bih, bhh,
                                          batch, pooled, (l == NL-1) ? 1 : 0);
    }

    k_head<<<NG, 256, 0, stream>>>(pooled, d1w, d1b, d2w, d2b, out);
}